// Round 2
// baseline (526.466 us; speedup 1.0000x reference)
//
#include <hip/hip_runtime.h>
#include <math.h>

#define N 4096
#define Dm 1024
#define BM 64
#define BN 64
#define BK 16
#define NCB (N / BN)   // 64 column-blocks per row
#define LDSP 68        // BM + 4 pad: keeps 16B alignment for float4 LDS reads, breaks store conflicts

// Kernel 1: per-row diag dot (D[i] = a_i . p_i), per-row L2 partial.
__global__ __launch_bounds__(256) void diag_l2_kernel(const float* __restrict__ A,
                                                      const float* __restrict__ P,
                                                      float* __restrict__ D,
                                                      float* __restrict__ rowl2) {
    int row = blockIdx.x;
    int t = threadIdx.x;                       // 256 threads, 1024 floats/row -> one float4 each
    const float4* a4 = (const float4*)(A + (size_t)row * Dm);
    const float4* p4 = (const float4*)(P + (size_t)row * Dm);
    float4 a = a4[t], p = p4[t];
    float dot = a.x * p.x + a.y * p.y + a.z * p.z + a.w * p.w;
    float l2  = a.x * a.x + a.y * a.y + a.z * a.z + a.w * a.w
              + p.x * p.x + p.y * p.y + p.z * p.z + p.w * p.w;
#pragma unroll
    for (int off = 32; off; off >>= 1) {
        dot += __shfl_xor(dot, off, 64);
        l2  += __shfl_xor(l2,  off, 64);
    }
    __shared__ float sd[4], sl[4];
    int wave = t >> 6;
    if ((t & 63) == 0) { sd[wave] = dot; sl[wave] = l2; }
    __syncthreads();
    if (t == 0) {
        D[row]     = sd[0] + sd[1] + sd[2] + sd[3];
        rowl2[row] = sl[0] + sl[1] + sl[2] + sl[3];
    }
}

// Kernel 2: tiled fp32 GEMM (S = A.P^T), fused per-row-per-colblock (max, sum exp(x-max)).
// x[i,j] = S[i,j] - D[i], diagonal masked to -inf. No atomics: each (row, colblock)
// partial is owned by exactly one block.
__global__ __launch_bounds__(256) void npair_main(const float* __restrict__ A,
                                                  const float* __restrict__ P,
                                                  const float* __restrict__ D,
                                                  float* __restrict__ Mpart,
                                                  float* __restrict__ Spart) {
    __shared__ float As[BK][LDSP];
    __shared__ float Bs[BK][LDSP];
    int bx = blockIdx.x, by = blockIdx.y;
    int tid = threadIdx.x;
    int tx = tid & 15, ty = tid >> 4;          // 16x16 threads, 4x4 outputs each
    int row0 = by * BM, col0 = bx * BN;
    int lr = tid >> 2;                          // 0..63: tile row being staged
    int lk = (tid & 3) << 2;                    // 0,4,8,12: k offset being staged
    float acc[4][4] = {};
    const float* Abase = A + (size_t)(row0 + lr) * Dm + lk;
    const float* Pbase = P + (size_t)(col0 + lr) * Dm + lk;

    for (int kt = 0; kt < Dm; kt += BK) {
        float4 av = *(const float4*)(Abase + kt);
        float4 bv = *(const float4*)(Pbase + kt);
        __syncthreads();
        As[lk + 0][lr] = av.x; As[lk + 1][lr] = av.y; As[lk + 2][lr] = av.z; As[lk + 3][lr] = av.w;
        Bs[lk + 0][lr] = bv.x; Bs[lk + 1][lr] = bv.y; Bs[lk + 2][lr] = bv.z; Bs[lk + 3][lr] = bv.w;
        __syncthreads();
#pragma unroll
        for (int k = 0; k < BK; ++k) {
            float4 af = *(const float4*)&As[k][ty << 2];
            float4 bf = *(const float4*)&Bs[k][tx << 2];
            acc[0][0] += af.x * bf.x; acc[0][1] += af.x * bf.y; acc[0][2] += af.x * bf.z; acc[0][3] += af.x * bf.w;
            acc[1][0] += af.y * bf.x; acc[1][1] += af.y * bf.y; acc[1][2] += af.y * bf.z; acc[1][3] += af.y * bf.w;
            acc[2][0] += af.z * bf.x; acc[2][1] += af.z * bf.y; acc[2][2] += af.z * bf.z; acc[2][3] += af.z * bf.w;
            acc[3][0] += af.w * bf.x; acc[3][1] += af.w * bf.y; acc[3][2] += af.w * bf.z; acc[3][3] += af.w * bf.w;
        }
    }

    // Epilogue: per-row tile max + sum of exp(x - max) over this block's 64 columns.
#pragma unroll
    for (int r = 0; r < 4; ++r) {
        int gr = row0 + (ty << 2) + r;
        float Dv = D[gr];
        float x[4];
        float m = -INFINITY;
#pragma unroll
        for (int c = 0; c < 4; ++c) {
            int gc = col0 + (tx << 2) + c;
            x[c] = (gr == gc) ? -INFINITY : (acc[r][c] - Dv);
            m = fmaxf(m, x[c]);
        }
        // max across the 16 tx lanes owning this row's columns (off<=8 stays in group)
#pragma unroll
        for (int off = 8; off; off >>= 1) m = fmaxf(m, __shfl_xor(m, off, 64));
        float rs = 0.0f;
#pragma unroll
        for (int c = 0; c < 4; ++c) rs += expf(x[c] - m);   // exp(-inf)=0 for diag
#pragma unroll
        for (int off = 8; off; off >>= 1) rs += __shfl_xor(rs, off, 64);
        if (tx == 0) {
            Mpart[(size_t)gr * NCB + bx] = m;
            Spart[(size_t)gr * NCB + bx] = rs;
        }
    }
}

// Kernel 3: combine partials per row: loss[i] = m + log(exp(-m) + sum s_k * exp(m_k - m))
// One wave (64 lanes) per row; 4 rows per 256-thread block.
__global__ __launch_bounds__(256) void combine_rows(const float* __restrict__ Mpart,
                                                    const float* __restrict__ Spart,
                                                    float* __restrict__ loss) {
    int t = threadIdx.x;
    int lane = t & 63;
    int row = blockIdx.x * 4 + (t >> 6);
    float mp = Mpart[(size_t)row * NCB + lane];
    float sp = Spart[(size_t)row * NCB + lane];
    float m = mp;
#pragma unroll
    for (int off = 32; off; off >>= 1) m = fmaxf(m, __shfl_xor(m, off, 64));
    float s = sp * expf(mp - m);
#pragma unroll
    for (int off = 32; off; off >>= 1) s += __shfl_xor(s, off, 64);
    if (lane == 0) loss[row] = m + logf(expf(-m) + s);   // = log1p(sum exp(x)), overflow-safe
}

// Kernel 4: final scalar: mean(loss) + 0.02 * sum(rowl2)/N
__global__ __launch_bounds__(256) void final_reduce(const float* __restrict__ loss,
                                                    const float* __restrict__ rowl2,
                                                    float* __restrict__ out) {
    int t = threadIdx.x;
    float accL = 0.0f, acc2 = 0.0f;
    for (int i = t; i < N; i += 256) {
        accL += loss[i];
        acc2 += rowl2[i];
    }
#pragma unroll
    for (int off = 32; off; off >>= 1) {
        accL += __shfl_xor(accL, off, 64);
        acc2 += __shfl_xor(acc2, off, 64);
    }
    __shared__ float sa[4], sb[4];
    int wave = t >> 6;
    if ((t & 63) == 0) { sa[wave] = accL; sb[wave] = acc2; }
    __syncthreads();
    if (t == 0) {
        float L  = sa[0] + sa[1] + sa[2] + sa[3];
        float l2 = sb[0] + sb[1] + sb[2] + sb[3];
        out[0] = L / (float)N + 0.02f * (l2 / (float)N);
    }
}

extern "C" void kernel_launch(void* const* d_in, const int* in_sizes, int n_in,
                              void* d_out, int out_size, void* d_ws, size_t ws_size,
                              hipStream_t stream) {
    const float* A = (const float*)d_in[0];
    const float* P = (const float*)d_in[1];
    float* out = (float*)d_out;
    float* D     = (float*)d_ws;          // N
    float* rowl2 = D + N;                 // N
    float* loss  = rowl2 + N;             // N
    float* Mpart = loss + N;              // N * NCB
    float* Spart = Mpart + (size_t)N * NCB; // N * NCB   (total ~2.1 MiB)

    diag_l2_kernel<<<N, 256, 0, stream>>>(A, P, D, rowl2);
    dim3 grid(N / BN, N / BM);
    npair_main<<<grid, 256, 0, stream>>>(A, P, D, Mpart, Spart);
    combine_rows<<<N / 4, 256, 0, stream>>>(Mpart, Spart, loss);
    final_reduce<<<1, 256, 0, stream>>>(loss, rowl2, out);
}

// Round 3
// 141.601 us; speedup vs baseline: 3.7179x; 3.7179x over previous
//
#include <hip/hip_runtime.h>
#include <math.h>
#include <stdint.h>

#define N 4096
#define Dm 1024
#define BM 128
#define BN 128
#define BK 32
#define NCB (N / 64)   // 64 column-partials per row (two 64-wide wave-columns per 128-block)

typedef __attribute__((ext_vector_type(8))) short bf16x8;
typedef __attribute__((ext_vector_type(4))) float f32x4;

typedef const void __attribute__((address_space(1)))* gas_t;
typedef void __attribute__((address_space(3)))* las_t;

static __device__ __forceinline__ void gload_lds16(const void* g, void* l) {
    // async global->LDS, 16B per lane; LDS dest must be wave-uniform base + lane*16
    __builtin_amdgcn_global_load_lds((gas_t)g, (las_t)l, 16, 0, 0);
}

static __device__ __forceinline__ unsigned short f2bf(float f) {
    unsigned int u = __float_as_uint(f);
    unsigned int r = (u + 0x7fff + ((u >> 16) & 1)) >> 16;  // RNE
    return (unsigned short)r;
}

// Kernel 1: convert A,P -> bf16 (row-major, K contiguous) + per-row diag dot + L2 partial.
__global__ __launch_bounds__(256) void prep_kernel(const float* __restrict__ A,
                                                   const float* __restrict__ P,
                                                   unsigned short* __restrict__ Abf,
                                                   unsigned short* __restrict__ Pbf,
                                                   float* __restrict__ D,
                                                   float* __restrict__ rowl2) {
    int row = blockIdx.x;
    int t = threadIdx.x;                       // 256 threads x float4 = 1024 floats/row
    const float4* a4 = (const float4*)(A + (size_t)row * Dm);
    const float4* p4 = (const float4*)(P + (size_t)row * Dm);
    float4 a = a4[t], p = p4[t];
    ushort4 ab, pb;
    ab.x = f2bf(a.x); ab.y = f2bf(a.y); ab.z = f2bf(a.z); ab.w = f2bf(a.w);
    pb.x = f2bf(p.x); pb.y = f2bf(p.y); pb.z = f2bf(p.z); pb.w = f2bf(p.w);
    ((ushort4*)(Abf + (size_t)row * Dm))[t] = ab;
    ((ushort4*)(Pbf + (size_t)row * Dm))[t] = pb;
    float dot = a.x * p.x + a.y * p.y + a.z * p.z + a.w * p.w;
    float l2  = a.x * a.x + a.y * a.y + a.z * a.z + a.w * a.w
              + p.x * p.x + p.y * p.y + p.z * p.z + p.w * p.w;
#pragma unroll
    for (int off = 32; off; off >>= 1) {
        dot += __shfl_xor(dot, off, 64);
        l2  += __shfl_xor(l2,  off, 64);
    }
    __shared__ float sd[4], sl[4];
    int wave = t >> 6;
    if ((t & 63) == 0) { sd[wave] = dot; sl[wave] = l2; }
    __syncthreads();
    if (t == 0) {
        D[row]     = sd[0] + sd[1] + sd[2] + sd[3];
        rowl2[row] = sl[0] + sl[1] + sl[2] + sl[3];
    }
}

// Kernel 2: bf16 MFMA GEMM (S = A.P^T, NT), m97 structure: 128x128 tile, BK=32,
// global_load_lds(16B) staging, 4 waves of 4x4 16x16x32 frags. Fused epilogue:
// per-row (max, sum exp(x-max)) over each wave's 64 columns -> partials (no atomics).
__global__ __launch_bounds__(256) void npair_mfma(const unsigned short* __restrict__ Abf,
                                                  const unsigned short* __restrict__ Pbf,
                                                  const float* __restrict__ D,
                                                  float* __restrict__ Mpart,
                                                  float* __restrict__ Spart) {
    __shared__ unsigned short At[BM * BK];   // [row][k], row stride 32 bf16 = 64B
    __shared__ unsigned short Bt[BN * BK];
    int tid = threadIdx.x;
    int wid = tid >> 6, lane = tid & 63;
    int wr = wid >> 1, wc = wid & 1;         // 2x2 waves, each owns 64x64 output
    int row0 = blockIdx.y * BM, col0 = blockIdx.x * BN;

    // loader mapping: slot L in [0,512) covers tile row L/4, k-chunk (L%3)*8.. wait (L&3)*8
    int r0 = tid >> 2,        kq0 = (tid & 3) << 3;          // L = tid
    int r1 = (256 + tid) >> 2, kq1 = (tid & 3) << 3;         // L = 256+tid (same kq pattern)
    const unsigned short* Ag0 = Abf + (size_t)(row0 + r0) * Dm + kq0;
    const unsigned short* Ag1 = Abf + (size_t)(row0 + r1) * Dm + kq1;
    const unsigned short* Bg0 = Pbf + (size_t)(col0 + r0) * Dm + kq0;
    const unsigned short* Bg1 = Pbf + (size_t)(col0 + r1) * Dm + kq1;
    unsigned short* Al0 = At + (size_t)tid * 8;
    unsigned short* Al1 = At + (size_t)(256 + tid) * 8;
    unsigned short* Bl0 = Bt + (size_t)tid * 8;
    unsigned short* Bl1 = Bt + (size_t)(256 + tid) * 8;

    f32x4 acc[4][4] = {};

    for (int kt = 0; kt < Dm; kt += BK) {
        __syncthreads();                      // prior frag reads (lgkm) done before overwrite
        gload_lds16(Ag0 + kt, Al0);
        gload_lds16(Ag1 + kt, Al1);
        gload_lds16(Bg0 + kt, Bl0);
        gload_lds16(Bg1 + kt, Bl1);
        __syncthreads();                      // drains vmcnt(0): LDS tiles ready

        bf16x8 af[4], bfr[4];
#pragma unroll
        for (int i = 0; i < 4; ++i) {
            int arow = wr * 64 + i * 16 + (lane & 15);
            af[i]  = *(const bf16x8*)(At + arow * BK + ((lane >> 4) << 3));
            int brow = wc * 64 + i * 16 + (lane & 15);
            bfr[i] = *(const bf16x8*)(Bt + brow * BK + ((lane >> 4) << 3));
        }
#pragma unroll
        for (int i = 0; i < 4; ++i)
#pragma unroll
            for (int j = 0; j < 4; ++j)
                acc[i][j] = __builtin_amdgcn_mfma_f32_16x16x32_bf16(af[i], bfr[j], acc[i][j], 0, 0, 0);
    }

    // Epilogue. C/D layout: col = lane&15, row = (lane>>4)*4 + reg  [m89/m91 verified]
    int cb = blockIdx.x * 2 + wc;            // column-partial slot, NCB=64 per row
#pragma unroll
    for (int rt = 0; rt < 4; ++rt) {
        int rbase = row0 + wr * 64 + rt * 16 + ((lane >> 4) << 2);
#pragma unroll
        for (int e = 0; e < 4; ++e) {
            int gr = rbase + e;
            float Dv = D[gr];
            float xs[4];
            float m = -INFINITY;
#pragma unroll
            for (int ct = 0; ct < 4; ++ct) {
                int gc = col0 + wc * 64 + ct * 16 + (lane & 15);
                float x = acc[rt][ct][e] - Dv;
                if (gr == gc) x = -INFINITY;  // mask diagonal
                xs[ct] = x;
                m = fmaxf(m, x);
            }
#pragma unroll
            for (int off = 8; off; off >>= 1) m = fmaxf(m, __shfl_xor(m, off, 64));
            float s = 0.0f;
#pragma unroll
            for (int ct = 0; ct < 4; ++ct) s += __expf(xs[ct] - m);  // exp(-inf)=0 on diag
#pragma unroll
            for (int off = 8; off; off >>= 1) s += __shfl_xor(s, off, 64);
            if ((lane & 15) == 0) {
                Mpart[(size_t)gr * NCB + cb] = m;
                Spart[(size_t)gr * NCB + cb] = s;
            }
        }
    }
}

// Kernel 3: combine partials per row: loss[i] = m + log(exp(-m) + sum s_k * exp(m_k - m))
__global__ __launch_bounds__(256) void combine_rows(const float* __restrict__ Mpart,
                                                    const float* __restrict__ Spart,
                                                    float* __restrict__ loss) {
    int t = threadIdx.x;
    int lane = t & 63;
    int row = blockIdx.x * 4 + (t >> 6);
    float mp = Mpart[(size_t)row * NCB + lane];
    float sp = Spart[(size_t)row * NCB + lane];
    float m = mp;
#pragma unroll
    for (int off = 32; off; off >>= 1) m = fmaxf(m, __shfl_xor(m, off, 64));
    float s = sp * __expf(mp - m);
#pragma unroll
    for (int off = 32; off; off >>= 1) s += __shfl_xor(s, off, 64);
    if (lane == 0) loss[row] = m + logf(__expf(-m) + s);   // log1p(sum exp(x)), overflow-safe
}

// Kernel 4: final scalar: mean(loss) + 0.02 * sum(rowl2)/N
__global__ __launch_bounds__(256) void final_reduce(const float* __restrict__ loss,
                                                    const float* __restrict__ rowl2,
                                                    float* __restrict__ out) {
    int t = threadIdx.x;
    float accL = 0.0f, acc2 = 0.0f;
    for (int i = t; i < N; i += 256) {
        accL += loss[i];
        acc2 += rowl2[i];
    }
#pragma unroll
    for (int off = 32; off; off >>= 1) {
        accL += __shfl_xor(accL, off, 64);
        acc2 += __shfl_xor(acc2, off, 64);
    }
    __shared__ float sa[4], sb[4];
    int wave = t >> 6;
    if ((t & 63) == 0) { sa[wave] = accL; sb[wave] = acc2; }
    __syncthreads();
    if (t == 0) {
        float L  = sa[0] + sa[1] + sa[2] + sa[3];
        float l2 = sb[0] + sb[1] + sb[2] + sb[3];
        out[0] = L / (float)N + 0.02f * (l2 / (float)N);
    }
}

extern "C" void kernel_launch(void* const* d_in, const int* in_sizes, int n_in,
                              void* d_out, int out_size, void* d_ws, size_t ws_size,
                              hipStream_t stream) {
    const float* A = (const float*)d_in[0];
    const float* P = (const float*)d_in[1];
    float* out = (float*)d_out;

    unsigned short* Abf = (unsigned short*)d_ws;            // N*Dm bf16 = 8 MiB
    unsigned short* Pbf = Abf + (size_t)N * Dm;             // 8 MiB
    float* D     = (float*)(Pbf + (size_t)N * Dm);          // N
    float* rowl2 = D + N;                                   // N
    float* loss  = rowl2 + N;                               // N
    float* Mpart = loss + N;                                // N*NCB = 1 MiB
    float* Spart = Mpart + (size_t)N * NCB;                 // 1 MiB

    prep_kernel<<<N, 256, 0, stream>>>(A, P, Abf, Pbf, D, rowl2);
    dim3 grid(N / BN, N / BM);
    npair_mfma<<<grid, 256, 0, stream>>>(Abf, Pbf, D, Mpart, Spart);
    combine_rows<<<N / 4, 256, 0, stream>>>(Mpart, Spart, loss);
    final_reduce<<<1, 256, 0, stream>>>(loss, rowl2, out);
}

// Round 4
// 132.089 us; speedup vs baseline: 3.9857x; 1.0720x over previous
//
#include <hip/hip_runtime.h>
#include <math.h>
#include <stdint.h>

#define N 4096
#define Dm 1024
#define BM 128
#define BN 128
#define BK 64
#define NCB (N / 64)   // 64 column-partials per row (two 64-wide wave-columns per 128-block)

typedef __attribute__((ext_vector_type(8))) short bf16x8;
typedef __attribute__((ext_vector_type(4))) float f32x4;

typedef const void __attribute__((address_space(1)))* gas_t;
typedef void __attribute__((address_space(3)))* las_t;

static __device__ __forceinline__ void gload_lds16(const void* g, void* l) {
    // async global->LDS, 16B per lane; LDS dest is wave-uniform base + lane*16
    __builtin_amdgcn_global_load_lds((gas_t)g, (las_t)l, 16, 0, 0);
}

static __device__ __forceinline__ unsigned short f2bf(float f) {
    unsigned int u = __float_as_uint(f);
    unsigned int r = (u + 0x7fff + ((u >> 16) & 1)) >> 16;  // RNE
    return (unsigned short)r;
}

// Kernel 1: convert A,P -> bf16 (row-major) + per-row diag dot + L2 partial.
__global__ __launch_bounds__(256) void prep_kernel(const float* __restrict__ A,
                                                   const float* __restrict__ P,
                                                   unsigned short* __restrict__ Abf,
                                                   unsigned short* __restrict__ Pbf,
                                                   float* __restrict__ D,
                                                   float* __restrict__ rowl2) {
    int row = blockIdx.x;
    int t = threadIdx.x;                       // 256 threads x float4 = 1024 floats/row
    const float4* a4 = (const float4*)(A + (size_t)row * Dm);
    const float4* p4 = (const float4*)(P + (size_t)row * Dm);
    float4 a = a4[t], p = p4[t];
    ushort4 ab, pb;
    ab.x = f2bf(a.x); ab.y = f2bf(a.y); ab.z = f2bf(a.z); ab.w = f2bf(a.w);
    pb.x = f2bf(p.x); pb.y = f2bf(p.y); pb.z = f2bf(p.z); pb.w = f2bf(p.w);
    ((ushort4*)(Abf + (size_t)row * Dm))[t] = ab;
    ((ushort4*)(Pbf + (size_t)row * Dm))[t] = pb;
    float dot = a.x * p.x + a.y * p.y + a.z * p.z + a.w * p.w;
    float l2  = a.x * a.x + a.y * a.y + a.z * a.z + a.w * a.w
              + p.x * p.x + p.y * p.y + p.z * p.z + p.w * p.w;
#pragma unroll
    for (int off = 32; off; off >>= 1) {
        dot += __shfl_xor(dot, off, 64);
        l2  += __shfl_xor(l2,  off, 64);
    }
    __shared__ float sd[4], sl[4];
    int wave = t >> 6;
    if ((t & 63) == 0) { sd[wave] = dot; sl[wave] = l2; }
    __syncthreads();
    if (t == 0) {
        D[row]     = sd[0] + sd[1] + sd[2] + sd[3];
        rowl2[row] = sl[0] + sl[1] + sl[2] + sl[3];
    }
}

// Kernel 2: bf16 MFMA GEMM, 128x128 tile, BK=64, XOR-swizzled LDS (conflict-free
// ds_read_b128), global_load_lds(16B) staging, fused flash-style epilogue.
__global__ __launch_bounds__(256) void npair_mfma(const unsigned short* __restrict__ Abf,
                                                  const unsigned short* __restrict__ Pbf,
                                                  const float* __restrict__ D,
                                                  float* __restrict__ Mpart,
                                                  float* __restrict__ Spart) {
    __shared__ unsigned short At[BM * BK];   // 16 KB, row stride 128 B = 32 banks
    __shared__ unsigned short Bt[BN * BK];   // 16 KB
    __shared__ float Ds[BM];
    int tid = threadIdx.x;
    int wid = tid >> 6, lane = tid & 63;
    int wr = wid >> 1, wc = wid & 1;         // 2x2 waves, each owns 64x64 output
    int row0 = blockIdx.y * BM, col0 = blockIdx.x * BN;

    // Loader: slot L (0..1023 per tile) -> LDS offset L*16B = row(L>>3)*128B + (L&7)*16B.
    // Slot (row, c) holds global k-chunk (c ^ (row&7))  [chunk = 16B = 8 bf16].
    // Swizzle is applied in the GLOBAL fetch address; LDS dest stays lane-ordered.
    const unsigned short* gA[4]; const unsigned short* gB[4];
    unsigned short* lA[4]; unsigned short* lB[4];
#pragma unroll
    for (int b = 0; b < 4; ++b) {
        int L = b * 256 + tid;
        int row = L >> 3, c = L & 7;
        int kch = c ^ (row & 7);
        gA[b] = Abf + (size_t)(row0 + row) * Dm + (kch << 3);
        gB[b] = Pbf + (size_t)(col0 + row) * Dm + (kch << 3);
        lA[b] = At + (size_t)L * 8;
        lB[b] = Bt + (size_t)L * 8;
    }
    if (tid < BM) Ds[tid] = D[row0 + tid];

    f32x4 acc[4][4] = {};

    for (int kt = 0; kt < Dm; kt += BK) {
        __syncthreads();                      // prior frag reads done before overwrite
#pragma unroll
        for (int b = 0; b < 4; ++b) {
            gload_lds16(gA[b] + kt, lA[b]);
            gload_lds16(gB[b] + kt, lB[b]);
        }
        __syncthreads();                      // drains vmcnt(0): LDS tiles ready
#pragma unroll
        for (int ks = 0; ks < 2; ++ks) {
            bf16x8 af[4], bfr[4];
#pragma unroll
            for (int i = 0; i < 4; ++i) {
                int g = (ks << 2) + (lane >> 4);          // global chunk 0..7 in this row
                int arow = wr * 64 + i * 16 + (lane & 15);
                af[i]  = *(const bf16x8*)(At + arow * BK + ((g ^ (arow & 7)) << 3));
                int brow = wc * 64 + i * 16 + (lane & 15);
                bfr[i] = *(const bf16x8*)(Bt + brow * BK + ((g ^ (brow & 7)) << 3));
            }
#pragma unroll
            for (int i = 0; i < 4; ++i)
#pragma unroll
                for (int j = 0; j < 4; ++j)
                    acc[i][j] = __builtin_amdgcn_mfma_f32_16x16x32_bf16(af[i], bfr[j], acc[i][j], 0, 0, 0);
        }
    }

    // Epilogue. C/D layout: col = lane&15, row = (lane>>4)*4 + reg  [m89/m91 verified]
    int cb = blockIdx.x * 2 + wc;            // column-partial slot, NCB=64 per row
#pragma unroll
    for (int rt = 0; rt < 4; ++rt) {
        int rloc = wr * 64 + rt * 16 + ((lane >> 4) << 2);
#pragma unroll
        for (int e = 0; e < 4; ++e) {
            int gr = row0 + rloc + e;
            float Dv = Ds[rloc + e];
            float xs[4];
            float m = -INFINITY;
#pragma unroll
            for (int ct = 0; ct < 4; ++ct) {
                int gc = col0 + wc * 64 + ct * 16 + (lane & 15);
                float x = acc[rt][ct][e] - Dv;
                if (gr == gc) x = -INFINITY;  // mask diagonal
                xs[ct] = x;
                m = fmaxf(m, x);
            }
#pragma unroll
            for (int off = 8; off; off >>= 1) m = fmaxf(m, __shfl_xor(m, off, 64));
            float s = 0.0f;
#pragma unroll
            for (int ct = 0; ct < 4; ++ct) s += __expf(xs[ct] - m);  // exp(-inf)=0 on diag
#pragma unroll
            for (int off = 8; off; off >>= 1) s += __shfl_xor(s, off, 64);
            if ((lane & 15) == 0) {
                Mpart[(size_t)gr * NCB + cb] = m;
                Spart[(size_t)gr * NCB + cb] = s;
            }
        }
    }
}

// Kernel 3: combine partials per row: loss[i] = m + log(exp(-m) + sum s_k * exp(m_k - m))
__global__ __launch_bounds__(256) void combine_rows(const float* __restrict__ Mpart,
                                                    const float* __restrict__ Spart,
                                                    float* __restrict__ loss) {
    int t = threadIdx.x;
    int lane = t & 63;
    int row = blockIdx.x * 4 + (t >> 6);
    float mp = Mpart[(size_t)row * NCB + lane];
    float sp = Spart[(size_t)row * NCB + lane];
    float m = mp;
#pragma unroll
    for (int off = 32; off; off >>= 1) m = fmaxf(m, __shfl_xor(m, off, 64));
    float s = sp * __expf(mp - m);
#pragma unroll
    for (int off = 32; off; off >>= 1) s += __shfl_xor(s, off, 64);
    if (lane == 0) loss[row] = m + logf(__expf(-m) + s);   // log1p(sum exp(x)), overflow-safe
}

// Kernel 4: final scalar: mean(loss) + 0.02 * sum(rowl2)/N
__global__ __launch_bounds__(256) void final_reduce(const float* __restrict__ loss,
                                                    const float* __restrict__ rowl2,
                                                    float* __restrict__ out) {
    int t = threadIdx.x;
    float accL = 0.0f, acc2 = 0.0f;
    for (int i = t; i < N; i += 256) {
        accL += loss[i];
        acc2 += rowl2[i];
    }
#pragma unroll
    for (int off = 32; off; off >>= 1) {
        accL += __shfl_xor(accL, off, 64);
        acc2 += __shfl_xor(acc2, off, 64);
    }
    __shared__ float sa[4], sb[4];
    int wave = t >> 6;
    if ((t & 63) == 0) { sa[wave] = accL; sb[wave] = acc2; }
    __syncthreads();
    if (t == 0) {
        float L  = sa[0] + sa[1] + sa[2] + sa[3];
        float l2 = sb[0] + sb[1] + sb[2] + sb[3];
        out[0] = L / (float)N + 0.02f * (l2 / (float)N);
    }
}

extern "C" void kernel_launch(void* const* d_in, const int* in_sizes, int n_in,
                              void* d_out, int out_size, void* d_ws, size_t ws_size,
                              hipStream_t stream) {
    const float* A = (const float*)d_in[0];
    const float* P = (const float*)d_in[1];
    float* out = (float*)d_out;

    unsigned short* Abf = (unsigned short*)d_ws;            // N*Dm bf16 = 8 MiB
    unsigned short* Pbf = Abf + (size_t)N * Dm;             // 8 MiB
    float* D     = (float*)(Pbf + (size_t)N * Dm);          // N
    float* rowl2 = D + N;                                   // N
    float* loss  = rowl2 + N;                               // N
    float* Mpart = loss + N;                                // N*NCB = 1 MiB
    float* Spart = Mpart + (size_t)N * NCB;                 // 1 MiB

    prep_kernel<<<N, 256, 0, stream>>>(A, P, Abf, Pbf, D, rowl2);
    dim3 grid(N / BN, N / BM);
    npair_mfma<<<grid, 256, 0, stream>>>(Abf, Pbf, D, Mpart, Spart);
    combine_rows<<<N / 4, 256, 0, stream>>>(Mpart, Spart, loss);
    final_reduce<<<1, 256, 0, stream>>>(loss, rowl2, out);
}